// Round 2
// baseline (32912.726 us; speedup 1.0000x reference)
//
#include <hip/hip_runtime.h>
#include <math.h>

// Problem constants
#define TT 2048
#define HZ 16
#define NBLK 32
#define NTH 512

// d_out layout (floats): pred | attw | q_gru_n | dec_gru_n | query_n
#define OUT_ATTW   (2048*64*64)            // 8388608
#define OUT_QGRU   (OUT_ATTW + 2048*8*64)  // 9437184
#define OUT_DECGRU (OUT_QGRU + 256)        // 9437440
#define OUT_QN     (OUT_DECGRU + 256)      // 9437696

// d_ws layout (bytes)
#define WSO_MB1    0                               // ulong[2][512] = 8192
#define WSO_ZEND   8192
#define WSO_GIFIX  14464                           // float[2048][768]
#define WSO_HIDFIX (WSO_GIFIX + 2048*768*4)        // float[2048][256]
#define WSO_W2T    (WSO_HIDFIX + 2048*256*4)       // float[256][64]
#define WSO_DAVA   (WSO_W2T + 256*64*4)            // float[2048][512]
#define WSO_DECH   (WSO_DAVA + 2048*512*4)         // float[2048][256]
#define WSO_FEAT   (WSO_DECH + 2048*256*4)         // float[2048][832]
#define WSO_SBUF   (WSO_FEAT + 2048*832*4)         // float[2048][256]
// qpart overlays the head of SBUF: ulong[8][512] = 32768 bytes.
// sbuf is only written (by gemm64) AFTER seq_kernel completes, so no conflict.
#define WSO_QPART  WSO_SBUF

__device__ __forceinline__ float warp_sum(float v) {
#pragma unroll
  for (int o = 32; o > 0; o >>= 1) v += __shfl_down(v, o, 64);
  return v;
}
__device__ __forceinline__ float warp_max(float v) {
#pragma unroll
  for (int o = 32; o > 0; o >>= 1) v = fmaxf(v, __shfl_down(v, o, 64));
  return v;
}
__device__ __forceinline__ float sigf(float x) { return 1.f / (1.f + __expf(-x)); }
__device__ __forceinline__ float dot4(float4 a, float4 b) {
  return a.x*b.x + a.y*b.y + a.z*b.z + a.w*b.w;
}
__device__ __forceinline__ unsigned long long aload64(const unsigned long long* p) {
  return __hip_atomic_load(p, __ATOMIC_RELAXED, __HIP_MEMORY_SCOPE_AGENT);
}
__device__ __forceinline__ void astore64(unsigned long long* p, unsigned long long v) {
  __hip_atomic_store(p, v, __ATOMIC_RELAXED, __HIP_MEMORY_SCOPE_AGENT);
}
__device__ __forceinline__ unsigned long long mbpack(float f, unsigned tag) {
  return ((unsigned long long)tag << 32) | (unsigned long long)__float_as_uint(f);
}
// Poll one tagged slot; payload rides the tag word (data-carrying barrier).
__device__ __forceinline__ float mbpoll(const unsigned long long* p, unsigned tag) {
  unsigned long long v = aload64(p);
  while ((unsigned)(v >> 32) != tag) {
    __builtin_amdgcn_s_sleep(1);
    v = aload64(p);
  }
  return __uint_as_float((unsigned)v);
}

// ---------------- transpose of dec_out_w ----------------
__global__ void transpose_k(const float* __restrict__ w2,   // [64,256]
                            float* __restrict__ w2T) {      // [256,64]
  int e = blockIdx.x * 256 + threadIdx.x;
  int r = e >> 6, a = e & 63;
  w2T[e] = w2[a * 256 + r];
}

// ---------------- generic tiled GEMM: C[t][r] = bias[r] + sum_k X[t][k]*W[r][woff+k]
__global__ void __launch_bounds__(256) gemm64(
    const float* __restrict__ X, int ldx,
    const float* __restrict__ W, int ldw, int woff,
    const float* __restrict__ bias,
    float* __restrict__ C, int crows, int K) {
  __shared__ float Xs[64 * 65];
  __shared__ float Ws[64 * 65];
  int t0 = blockIdx.x * 64, r0 = blockIdx.y * 64;
  int tid = threadIdx.x;
  int u = tid & 15, v = tid >> 4;
  float acc[4][4];
#pragma unroll
  for (int i = 0; i < 4; i++)
#pragma unroll
    for (int j = 0; j < 4; j++) acc[i][j] = 0.f;

  for (int kc = 0; kc < K; kc += 64) {
    for (int idx = tid; idx < 4096; idx += 256) {
      int row = idx >> 6, col = idx & 63;
      Xs[row * 65 + col] = X[(size_t)(t0 + row) * ldx + kc + col];
      Ws[row * 65 + col] = W[(size_t)(r0 + row) * ldw + woff + kc + col];
    }
    __syncthreads();
#pragma unroll 8
    for (int k = 0; k < 64; k++) {
      float xs[4], ws[4];
#pragma unroll
      for (int i = 0; i < 4; i++) xs[i] = Xs[(v + 16 * i) * 65 + k];
#pragma unroll
      for (int j = 0; j < 4; j++) ws[j] = Ws[(u + 16 * j) * 65 + k];
#pragma unroll
      for (int i = 0; i < 4; i++)
#pragma unroll
        for (int j = 0; j < 4; j++) acc[i][j] += xs[i] * ws[j];
    }
    __syncthreads();
  }
#pragma unroll
  for (int i = 0; i < 4; i++)
#pragma unroll
    for (int j = 0; j < 4; j++) {
      int t = t0 + v + 16 * i, r = r0 + u + 16 * j;
      C[(size_t)t * crows + r] = acc[i][j] + bias[r];
    }
}

// -------- fused sequential kernel --------
// Exchange 1 (h2|dech): tagged mailbox mb1, all 32 blocks write 16 slots each.
// Exchange 2 (query):   8 writer blocks (bid<8) each own 32 hid rows, publish
//                       tagged partial-query vectors; everyone polls 8 slots.
// ABA safety of single-buffered qpart: exchange-1's poll is an all-block
// rendezvous each step, so a writer cannot publish step t+1 before every
// block consumed step t.
__global__ void __launch_bounds__(512) seq_kernel(
    const float* __restrict__ x_fix,    // [2048,64]
    const float* __restrict__ x_att,    // [2048,64,64]
    const float* __restrict__ w_ih,     // [768,1088]
    const float* __restrict__ w_hh,     // [768,256]
    const float* __restrict__ b_hh,     // [768]
    const float* __restrict__ q_hid_w,  // [256,832]
    const float* __restrict__ wq,       // [256,512]
    const float* __restrict__ dwih,     // [768,576]
    const float* __restrict__ dwhh,     // [768,256]
    const float* __restrict__ dbih,     // [768]
    const float* __restrict__ dbhh,     // [768]
    const float* __restrict__ gi_fix,   // [2048,768]
    const float* __restrict__ hid_fix,  // [2048,256]
    unsigned long long* __restrict__ mb1,    // [2][512] h2|dech mailbox
    unsigned long long* __restrict__ qpart,  // [8][512] tagged query partials
    float* __restrict__ dava,           // [2048,512]
    float* __restrict__ dec_hist,       // [2048,256]
    float* __restrict__ out) {
  __shared__ float att_s[64 * 65];             // x_att tile (t)
  __shared__ float ring_s[16][512];            // attw ring
  __shared__ __align__(16) float avq_s[1024];  // [attv(512) | query(512)]
  __shared__ float qk_s[512];                  // attw(t)
  __shared__ __align__(16) float xcat_s[576];  // [fix(64) | dec_att_a(512)]
  __shared__ float hid32_s[32];                // writers' hid rows
  __shared__ __align__(16) float h_s[256];
  __shared__ __align__(16) float dech_s[256];
  __shared__ float g_s[4][8];
  __shared__ float dg_s[4][8];

  const int tid = threadIdx.x;
  const int bid = blockIdx.x;
  const int lane = tid & 63, wv = tid >> 6;  // wv 0..7 (one head / wave)
  const int wbid = bid & 7;                  // writer slice id

  // ---- preload writer weights into registers (occupancy is 1 block/CU;
  //      VGPRs are free). wB: q_hid_w rows wbid*32+wv*4+k, 3 float4/thread.
  //      wC: wq rows wbid*32+r, column tid.
  float4 wB[4][3];
#pragma unroll
  for (int k = 0; k < 4; k++) {
    const float4* W =
        (const float4*)(q_hid_w + (size_t)(wbid * 32 + wv * 4 + k) * 832);
    wB[k][0] = W[lane];        // cols   0..255  (h2)
    wB[k][1] = W[80 + lane];   // cols 320..575  (attv lo)
    wB[k][2] = W[144 + lane];  // cols 576..831  (attv hi)
  }
  float wC[32];
#pragma unroll
  for (int r = 0; r < 32; r++)
    wC[r] = wq[(size_t)(wbid * 32 + r) * 512 + tid];

  // init state + initial tile + fix(0)
  for (int i = tid; i < 1024; i += NTH) avq_s[i] = (i >= 512) ? 1.f : 0.f;
  if (tid < 256) { h_s[tid] = 0.f; dech_s[tid] = 0.f; }
  {
    const float4* g4 = (const float4*)x_att;
    float4 a = g4[tid * 2], b = g4[tid * 2 + 1];
    int row = tid >> 3, c0 = (tid & 7) * 8;
    float* d = &att_s[row * 65 + c0];
    d[0]=a.x; d[1]=a.y; d[2]=a.z; d[3]=a.w; d[4]=b.x; d[5]=b.y; d[6]=b.z; d[7]=b.w;
  }
  if (tid < 64) xcat_s[tid] = x_fix[tid];
  __syncthreads();

  for (int t = 0; t <= TT; ++t) {
    if (t > 0) {
      // ---- A: poll E1(t-1) — the all-block rendezvous ----
      {
        float f = mbpoll(mb1 + (size_t)((t - 1) & 1) * 512 + tid, (unsigned)t);
        int b = tid >> 4, j = tid & 15;
        if (j < 8) h_s[b * 8 + j] = f;
        else dech_s[b * 8 + j - 8] = f;
      }
      __syncthreads();
      // ---- B': writers compute their 32 hid(t-1) rows (reg weights) ----
      if (bid < 8) {
        const float4* h4 = (const float4*)h_s;
        const float4* a4 = (const float4*)avq_s;
        float4 vh = h4[lane], v1 = a4[lane], v2 = a4[64 + lane];
#pragma unroll
        for (int k = 0; k < 4; k++) {
          float acc = dot4(wB[k][0], vh) + dot4(wB[k][1], v1) + dot4(wB[k][2], v2);
          float s = warp_sum(acc);
          if (lane == 0)
            hid32_s[wv * 4 + k] = fmaxf(
                s + hid_fix[(size_t)(t - 1) * 256 + wbid * 32 + wv * 4 + k], 0.f);
        }
      }
      __syncthreads();
      // ---- C': writers publish tagged query partials ----
      if (bid < 8) {
        float part = 0.f;
#pragma unroll
        for (int r = 0; r < 32; r++) part += hid32_s[r] * wC[r];
        astore64(&qpart[(size_t)wbid * 512 + tid], mbpack(part, (unsigned)t));
      }
      // ---- E': poll 8 partial slots, sum in fixed order ----
      {
        unsigned long long v[8];
        for (;;) {
#pragma unroll
          for (int w = 0; w < 8; w++)
            v[w] = aload64(&qpart[(size_t)w * 512 + tid]);
          bool ok = true;
#pragma unroll
          for (int w = 0; w < 8; w++)
            ok = ok && ((unsigned)(v[w] >> 32) == (unsigned)t);
          if (ok) break;
          __builtin_amdgcn_s_sleep(1);
        }
        float qv = 0.f;
#pragma unroll
        for (int w = 0; w < 8; w++) qv += __uint_as_float((unsigned)v[w]);
        avq_s[512 + tid] = qv;
        if (t == TT) {
          if (bid == 0) {
            if (tid < 256) {
              out[OUT_QGRU + tid] = h_s[tid];
              out[OUT_DECGRU + tid] = dech_s[tid];
            }
            out[OUT_QN + tid] = qv;
          }
          break;
        }
      }
      __syncthreads();
    }

    // ---- F: prefetch tile(t+1) + attention(t), wave-local per head ----
    float4 pfa, pfb;
    {
      int tn = (t + 1 < TT) ? t + 1 : t;
      const float4* g4 = (const float4*)(x_att + (size_t)tn * 4096);
      pfa = g4[tid * 2];
      pfb = g4[tid * 2 + 1];
    }
    {
      float acc = 0.f;
#pragma unroll 16
      for (int a = 0; a < 64; a++)
        acc += avq_s[512 + wv * 64 + a] * att_s[lane * 65 + a];
      acc *= 0.125f;
      float m = __shfl(warp_max(acc), 0, 64);
      float e = __expf(acc - m);
      float s = __shfl(warp_sum(e), 0, 64);
      qk_s[wv * 64 + lane] = e / s;
    }
    {
      const float* rg = (t == 0) ? &qk_s[0] : ring_s[(t >= 16) ? (t & 15) : 0];
      float av = 0.f, dv = 0.f;
#pragma unroll 8
      for (int n = 0; n < 64; n++) {
        float xv = att_s[n * 65 + lane];
        av += qk_s[wv * 64 + n] * xv;
        dv += rg[wv * 64 + n] * xv;
      }
      avq_s[wv * 64 + lane] = av;
      xcat_s[64 + wv * 64 + lane] = dv;
    }
    __syncthreads();  // S-F
    // ---- G: q-GRU gates (3 rows/wave) + dec-GRU gates (3 rows/wave) ----
    {
      float accg[3], acch[3];
      int rows[3];
#pragma unroll
      for (int k = 0; k < 3; k++) {
        int m = wv * 3 + k;
        rows[k] = ((m >> 3) * 256) + bid * 8 + (m & 7);
        accg[k] = 0.f; acch[k] = 0.f;
      }
      const float4* in4 = (const float4*)avq_s;
#pragma unroll
      for (int c0 = 0; c0 < 4; c0++) {
        int c = lane + 64 * c0;
        float4 v = in4[c];
#pragma unroll
        for (int k = 0; k < 3; k++) {
          const float4* W = (const float4*)(w_ih + (size_t)rows[k] * 1088 + 64);
          accg[k] += dot4(W[c], v);
        }
      }
      {
        const float4* h4 = (const float4*)h_s;
        float4 vh = h4[lane];
#pragma unroll
        for (int k = 0; k < 3; k++) {
          const float4* Wh = (const float4*)(w_hh + (size_t)rows[k] * 256);
          acch[k] += dot4(Wh[lane], vh);
        }
      }
#pragma unroll
      for (int k = 0; k < 3; k++) {
        int m = wv * 3 + k;
        int gate = m >> 3, idx = m & 7;
        if (gate < 2) {
          float s = warp_sum(accg[k] + acch[k]);
          if (lane == 0)
            g_s[gate][idx] = s + gi_fix[(size_t)t * 768 + rows[k]] + b_hh[rows[k]];
        } else {
          float sg = warp_sum(accg[k]);
          float sh = warp_sum(acch[k]);
          if (lane == 0) {
            g_s[2][idx] = sg + gi_fix[(size_t)t * 768 + rows[k]];
            g_s[3][idx] = sh + b_hh[rows[k]];
          }
        }
      }
    }
    {
      float accg[3], acch[3];
      int rows[3];
#pragma unroll
      for (int k = 0; k < 3; k++) {
        int m = wv * 3 + k;
        rows[k] = ((m >> 3) * 256) + bid * 8 + (m & 7);
        accg[k] = 0.f; acch[k] = 0.f;
      }
      const float4* x4 = (const float4*)xcat_s;
#pragma unroll
      for (int c0 = 0; c0 < 3; c0++) {
        int c = lane + 64 * c0;
        if (c < 144) {
          float4 v = x4[c];
#pragma unroll
          for (int k = 0; k < 3; k++) {
            const float4* W = (const float4*)(dwih + (size_t)rows[k] * 576);
            accg[k] += dot4(W[c], v);
          }
        }
      }
      {
        const float4* dh4 = (const float4*)dech_s;
        float4 vh = dh4[lane];
#pragma unroll
        for (int k = 0; k < 3; k++) {
          const float4* Wh = (const float4*)(dwhh + (size_t)rows[k] * 256);
          acch[k] += dot4(Wh[lane], vh);
        }
      }
#pragma unroll
      for (int k = 0; k < 3; k++) {
        int m = wv * 3 + k;
        int gate = m >> 3, idx = m & 7;
        if (gate < 2) {
          float s = warp_sum(accg[k] + acch[k]);
          if (lane == 0)
            dg_s[gate][idx] = s + dbih[rows[k]] + dbhh[rows[k]];
        } else {
          float sg = warp_sum(accg[k]);
          float sh = warp_sum(acch[k]);
          if (lane == 0) {
            dg_s[2][idx] = sg + dbih[rows[k]];
            dg_s[3][idx] = sh + dbhh[rows[k]];
          }
        }
      }
    }
    __syncthreads();  // S-G
    // ---- H: combine + E1(t) write ASAP ----
    if (tid < 8) {
      float r = sigf(g_s[0][tid]), z = sigf(g_s[1][tid]);
      float nn = tanhf(g_s[2][tid] + r * g_s[3][tid]);
      float h2 = (1.f - z) * nn + z * h_s[bid * 8 + tid];
      astore64(&mb1[(size_t)(t & 1) * 512 + bid * 16 + tid],
               mbpack(h2, (unsigned)(t + 1)));
    } else if (tid < 16) {
      int i = tid - 8;
      float r = sigf(dg_s[0][i]), z = sigf(dg_s[1][i]);
      float nn = tanhf(dg_s[2][i] + r * dg_s[3][i]);
      float d2 = (1.f - z) * nn + z * dech_s[bid * 8 + i];
      astore64(&mb1[(size_t)(t & 1) * 512 + bid * 16 + tid],
               mbpack(d2, (unsigned)(t + 1)));
      dec_hist[(size_t)t * 256 + bid * 8 + i] = d2;
    }
    // ---- I: shadow work (under other blocks' E1 skew) ----
    if (tid < 16) {
      out[OUT_ATTW + (size_t)t * 512 + bid * 16 + tid] = qk_s[bid * 16 + tid];
      dava[(size_t)t * 512 + bid * 16 + tid] = xcat_s[64 + bid * 16 + tid];
    }
    ring_s[t & 15][tid] = qk_s[tid];
    {
      int row = tid >> 3, c0 = (tid & 7) * 8;
      float* d = &att_s[row * 65 + c0];
      d[0]=pfa.x; d[1]=pfa.y; d[2]=pfa.z; d[3]=pfa.w;
      d[4]=pfb.x; d[5]=pfb.y; d[6]=pfb.z; d[7]=pfb.w;
    }
    if (tid >= 448) {
      int i = tid - 448;
      int tn = (t + 1 < TT) ? t + 1 : t;
      xcat_s[i] = x_fix[tn * 64 + i];
    }
  }
}

// ---------------- feat assembly: [dec_h | x_fix | dec_att_a] ----------------
__global__ void featcopy(const float* __restrict__ dec_hist,
                         const float* __restrict__ x_fix,
                         const float* __restrict__ dava,
                         float* __restrict__ feat) {
  int t = blockIdx.x, tid = threadIdx.x;
  float* f = feat + (size_t)t * 832;
  f[tid] = dec_hist[(size_t)t * 256 + tid];
  if (tid < 64) f[256 + tid] = x_fix[t * 64 + tid];
  for (int i = tid; i < 512; i += 256) f[320 + i] = dava[(size_t)t * 512 + i];
}

// ---------------- final MLP ----------------
__global__ void __launch_bounds__(256) final_k(
    const float* __restrict__ x_att,
    const float* __restrict__ s,      // [2048,256] shared part incl. b1
    const float* __restrict__ w1,     // dec_hid_w [256,896]
    const float* __restrict__ w2T,    // [256,64]
    const float* __restrict__ b2,     // [64]
    float* __restrict__ pred) {
  __shared__ float att_s[4096];
  __shared__ float s_s[256];
  __shared__ float hid_s[32 * 256];
  int t = blockIdx.x, tid = threadIdx.x, lane = tid & 63, wv = tid >> 6;
  for (int i = tid; i < 4096; i += 256) att_s[i] = x_att[(size_t)t * 4096 + i];
  s_s[tid] = s[(size_t)t * 256 + tid];
  float4 w1v[16];
  const float4* W1a4 = (const float4*)(w1 + (size_t)tid * 896 + 832);
#pragma unroll
  for (int q = 0; q < 16; q++) w1v[q] = W1a4[q];
  float bb = b2[lane];
  __syncthreads();
  for (int ch = 0; ch < 2; ch++) {
    for (int nl = 0; nl < 32; nl++) {
      int n = ch * 32 + nl;
      const float4* a4 = (const float4*)(att_s + n * 64);
      float acc = s_s[tid];
#pragma unroll
      for (int q = 0; q < 16; q++) acc += dot4(w1v[q], a4[q]);
      hid_s[nl * 256 + tid] = fmaxf(acc, 0.f);
    }
    __syncthreads();
    float accb[8];
#pragma unroll
    for (int j = 0; j < 8; j++) accb[j] = bb;
    for (int r = 0; r < 256; r++) {
      float w = w2T[r * 64 + lane];
#pragma unroll
      for (int j = 0; j < 8; j++) accb[j] += w * hid_s[(wv * 8 + j) * 256 + r];
    }
#pragma unroll
    for (int j = 0; j < 8; j++) {
      int n = ch * 32 + wv * 8 + j;
      pred[(size_t)t * 4096 + n * 64 + lane] = fmaxf(accb[j], 0.f);
    }
    __syncthreads();
  }
}

extern "C" void kernel_launch(void* const* d_in, const int* in_sizes, int n_in,
                              void* d_out, int out_size, void* d_ws, size_t ws_size,
                              hipStream_t stream) {
  const float* x_fix = (const float*)d_in[0];
  const float* x_att = (const float*)d_in[1];
  const float* qwih = (const float*)d_in[3];
  const float* qwhh = (const float*)d_in[4];
  const float* qbih = (const float*)d_in[5];
  const float* qbhh = (const float*)d_in[6];
  const float* qhw = (const float*)d_in[7];
  const float* qhb = (const float*)d_in[8];
  const float* wq = (const float*)d_in[9];
  const float* dwih = (const float*)d_in[10];
  const float* dwhh = (const float*)d_in[11];
  const float* dbih = (const float*)d_in[12];
  const float* dbhh = (const float*)d_in[13];
  const float* w1 = (const float*)d_in[14];
  const float* b1 = (const float*)d_in[15];
  const float* w2 = (const float*)d_in[16];
  const float* b2 = (const float*)d_in[17];
  float* out = (float*)d_out;

  char* ws = (char*)d_ws;
  unsigned long long* mb1 = (unsigned long long*)(ws + WSO_MB1);
  unsigned long long* qpart = (unsigned long long*)(ws + WSO_QPART);
  float* gi_fix = (float*)(ws + WSO_GIFIX);
  float* hid_fix = (float*)(ws + WSO_HIDFIX);
  float* w2T = (float*)(ws + WSO_W2T);
  float* dava = (float*)(ws + WSO_DAVA);
  float* dec_hist = (float*)(ws + WSO_DECH);
  float* feat = (float*)(ws + WSO_FEAT);
  float* sbuf = (float*)(ws + WSO_SBUF);

  // zero mailbox tags + query-partial tags — required every launch
  hipMemsetAsync(ws, 0, WSO_ZEND, stream);
  hipMemsetAsync(ws + WSO_QPART, 0, 8 * 512 * 8, stream);

  transpose_k<<<64, 256, 0, stream>>>(w2, w2T);
  gemm64<<<dim3(32, 12), 256, 0, stream>>>(x_fix, 64, qwih, 1088, 0, qbih,
                                           gi_fix, 768, 64);
  gemm64<<<dim3(32, 4), 256, 0, stream>>>(x_fix, 64, qhw, 832, 256, qhb,
                                          hid_fix, 256, 64);

  seq_kernel<<<NBLK, NTH, 0, stream>>>(x_fix, x_att, qwih, qwhh, qbhh,
                                       qhw, wq, dwih, dwhh, dbih, dbhh,
                                       gi_fix, hid_fix, mb1, qpart,
                                       dava, dec_hist, out);

  featcopy<<<2048, 256, 0, stream>>>(dec_hist, x_fix, dava, feat);
  gemm64<<<dim3(32, 4), 256, 0, stream>>>(feat, 832, w1, 896, 0, b1,
                                          sbuf, 256, 832);
  final_k<<<2048, 256, 0, stream>>>(x_att, sbuf, w1, w2T, b2, out);
}

// Round 6
// 18350.345 us; speedup vs baseline: 1.7936x; 1.7936x over previous
//
#include <hip/hip_runtime.h>
#include <math.h>

// Problem constants
#define TT 2048
#define HZ 16
#define NBLK 32
#define NTH 512

// d_out layout (floats): pred | attw | q_gru_n | dec_gru_n | query_n
#define OUT_ATTW   (2048*64*64)            // 8388608
#define OUT_QGRU   (OUT_ATTW + 2048*8*64)  // 9437184
#define OUT_DECGRU (OUT_QGRU + 256)        // 9437440
#define OUT_QN     (OUT_DECGRU + 256)      // 9437696

// d_ws layout (bytes)
#define WSO_MB1    0                               // ulong[2][512] = 8192
#define WSO_QACC   8192                            // float[3][512] = 6144
#define WSO_QCNT   14336                           // unsigned + pad (128)
#define WSO_ZEND   14464
#define WSO_GIFIX  14464                           // float[2048][768]
#define WSO_HIDFIX (WSO_GIFIX + 2048*768*4)        // float[2048][256]
#define WSO_W2T    (WSO_HIDFIX + 2048*256*4)       // float[256][64]
#define WSO_DAVA   (WSO_W2T + 256*64*4)            // float[2048][512]
#define WSO_DECH   (WSO_DAVA + 2048*512*4)         // float[2048][256]
#define WSO_FEAT   (WSO_DECH + 2048*256*4)         // float[2048][832]
#define WSO_SBUF   (WSO_FEAT + 2048*832*4)         // float[2048][256]

__device__ __forceinline__ float warp_sum(float v) {
#pragma unroll
  for (int o = 32; o > 0; o >>= 1) v += __shfl_down(v, o, 64);
  return v;
}
__device__ __forceinline__ float warp_max(float v) {
#pragma unroll
  for (int o = 32; o > 0; o >>= 1) v = fmaxf(v, __shfl_down(v, o, 64));
  return v;
}
__device__ __forceinline__ float sigf(float x) { return 1.f / (1.f + __expf(-x)); }
__device__ __forceinline__ float dot4(float4 a, float4 b) {
  return a.x*b.x + a.y*b.y + a.z*b.z + a.w*b.w;
}
__device__ __forceinline__ unsigned long long aload64(const unsigned long long* p) {
  return __hip_atomic_load(p, __ATOMIC_RELAXED, __HIP_MEMORY_SCOPE_AGENT);
}
__device__ __forceinline__ void astore64(unsigned long long* p, unsigned long long v) {
  __hip_atomic_store(p, v, __ATOMIC_RELAXED, __HIP_MEMORY_SCOPE_AGENT);
}
__device__ __forceinline__ unsigned long long mbpack(float f, unsigned tag) {
  return ((unsigned long long)tag << 32) | (unsigned long long)__float_as_uint(f);
}
// Poll one tagged slot; payload rides the tag word (data-carrying barrier).
__device__ __forceinline__ float mbpoll(const unsigned long long* p, unsigned tag) {
  unsigned long long v = aload64(p);
  while ((unsigned)(v >> 32) != tag) {
    __builtin_amdgcn_s_sleep(1);
    v = aload64(p);
  }
  return __uint_as_float((unsigned)v);
}

// ---------------- transpose of dec_out_w ----------------
__global__ void transpose_k(const float* __restrict__ w2,   // [64,256]
                            float* __restrict__ w2T) {      // [256,64]
  int e = blockIdx.x * 256 + threadIdx.x;
  int r = e >> 6, a = e & 63;
  w2T[e] = w2[a * 256 + r];
}

// ---------------- generic tiled GEMM: C[t][r] = bias[r] + sum_k X[t][k]*W[r][woff+k]
__global__ void __launch_bounds__(256) gemm64(
    const float* __restrict__ X, int ldx,
    const float* __restrict__ W, int ldw, int woff,
    const float* __restrict__ bias,
    float* __restrict__ C, int crows, int K) {
  __shared__ float Xs[64 * 65];
  __shared__ float Ws[64 * 65];
  int t0 = blockIdx.x * 64, r0 = blockIdx.y * 64;
  int tid = threadIdx.x;
  int u = tid & 15, v = tid >> 4;
  float acc[4][4];
#pragma unroll
  for (int i = 0; i < 4; i++)
#pragma unroll
    for (int j = 0; j < 4; j++) acc[i][j] = 0.f;

  for (int kc = 0; kc < K; kc += 64) {
    for (int idx = tid; idx < 4096; idx += 256) {
      int row = idx >> 6, col = idx & 63;
      Xs[row * 65 + col] = X[(size_t)(t0 + row) * ldx + kc + col];
      Ws[row * 65 + col] = W[(size_t)(r0 + row) * ldw + woff + kc + col];
    }
    __syncthreads();
#pragma unroll 8
    for (int k = 0; k < 64; k++) {
      float xs[4], ws[4];
#pragma unroll
      for (int i = 0; i < 4; i++) xs[i] = Xs[(v + 16 * i) * 65 + k];
#pragma unroll
      for (int j = 0; j < 4; j++) ws[j] = Ws[(u + 16 * j) * 65 + k];
#pragma unroll
      for (int i = 0; i < 4; i++)
#pragma unroll
        for (int j = 0; j < 4; j++) acc[i][j] += xs[i] * ws[j];
    }
    __syncthreads();
  }
#pragma unroll
  for (int i = 0; i < 4; i++)
#pragma unroll
    for (int j = 0; j < 4; j++) {
      int t = t0 + v + 16 * i, r = r0 + u + 16 * j;
      C[(size_t)t * crows + r] = acc[i][j] + bias[r];
    }
}

// -------- fused sequential kernel --------
// Exchange 1 (h2|dech): tagged mailbox mb1 (proven).
// Exchange 2 (query):   atomicAdd partials -> counter arrive/poll -> re-read
//                       (proven; Round-1's scatter-poll variant regressed:
//                       agent-scope polls bypass L2, +250MB FETCH, +4.6us/step).
// New this round: (a) arrive split from poll; (b) dec-GRU work (no query dep)
// runs between arrive and poll, hidden under arrival skew; (c) critical-path
// weights (q-gates, q_hid row, wq slice, biases) preloaded into VGPRs.
__global__ void __launch_bounds__(512) seq_kernel(
    const float* __restrict__ x_fix,    // [2048,64]
    const float* __restrict__ x_att,    // [2048,64,64]
    const float* __restrict__ w_ih,     // [768,1088]
    const float* __restrict__ w_hh,     // [768,256]
    const float* __restrict__ b_hh,     // [768]
    const float* __restrict__ q_hid_w,  // [256,832]
    const float* __restrict__ wq,       // [256,512]
    const float* __restrict__ dwih,     // [768,576]
    const float* __restrict__ dwhh,     // [768,256]
    const float* __restrict__ dbih,     // [768]
    const float* __restrict__ dbhh,     // [768]
    const float* __restrict__ gi_fix,   // [2048,768]
    const float* __restrict__ hid_fix,  // [2048,256]
    unsigned long long* __restrict__ mb1,  // [2][512] h2|dech mailbox
    float* __restrict__ qacc,           // [3][512] query accumulator
    unsigned* __restrict__ qcnt,        // arrival counter (monotonic)
    float* __restrict__ dava,           // [2048,512]
    float* __restrict__ dec_hist,       // [2048,256]
    float* __restrict__ out) {
  __shared__ float att_s[64 * 65];             // x_att tile (t)
  __shared__ float ring_s[16][512];            // attw ring
  __shared__ __align__(16) float avq_s[1024];  // [attv(512) | query(512)]
  __shared__ float qk_s[512];                  // attw(t)
  __shared__ __align__(16) float xcat_s[576];  // [fix(64) | dec_att_a(512)]
  __shared__ __align__(16) float hid8_s[8];
  __shared__ __align__(16) float h_s[256];
  __shared__ __align__(16) float dech_s[256];
  __shared__ float g_s[4][8];
  __shared__ float dg_s[4][8];

  const int tid = threadIdx.x;
  const int bid = blockIdx.x;
  const int lane = tid & 63, wv = tid >> 6;  // wv 0..7 (one head / wave)

  // ---- gate-row indices (3 rows/wave, same formula for q and dec GRUs) ----
  int rowsQ[3];
#pragma unroll
  for (int k = 0; k < 3; k++) {
    int m = wv * 3 + k;
    rowsQ[k] = ((m >> 3) * 256) + bid * 8 + (m & 7);
  }

  // ---- VGPR preloads (1 block/CU -> registers are free up to ~256) ----
  float4 wGi[3][4];  // q-GRU w_ih slice (cols 64..1087)
  float4 wGh[3];     // q-GRU w_hh slice
  float bhh_r[3], dbi_r[3], dbh_r[3];
#pragma unroll
  for (int k = 0; k < 3; k++) {
    const float4* Wi = (const float4*)(w_ih + (size_t)rowsQ[k] * 1088 + 64);
#pragma unroll
    for (int c0 = 0; c0 < 4; c0++) wGi[k][c0] = Wi[lane + 64 * c0];
    wGh[k] = ((const float4*)(w_hh + (size_t)rowsQ[k] * 256))[lane];
    bhh_r[k] = b_hh[rowsQ[k]];
    dbi_r[k] = dbih[rowsQ[k]];
    dbh_r[k] = dbhh[rowsQ[k]];
  }
  float4 wBq[3];     // q_hid_w row (bid*8+wv): h2 | attv-lo | attv-hi
  {
    const float4* W = (const float4*)(q_hid_w + (size_t)(bid * 8 + wv) * 832);
    wBq[0] = W[lane];
    wBq[1] = W[80 + lane];
    wBq[2] = W[144 + lane];
  }
  float wqr[8];      // wq[(bid*8+r)][tid]
#pragma unroll
  for (int r = 0; r < 8; r++) wqr[r] = wq[(size_t)(bid * 8 + r) * 512 + tid];

  // dec gates: shared-state lambda (weights stay in L2 — off critical path)
  auto dec_gates = [&]() {
    float accg[3], acch[3];
#pragma unroll
    for (int k = 0; k < 3; k++) { accg[k] = 0.f; acch[k] = 0.f; }
    const float4* x4 = (const float4*)xcat_s;
#pragma unroll
    for (int c0 = 0; c0 < 3; c0++) {
      int c = lane + 64 * c0;
      if (c < 144) {
        float4 v = x4[c];
#pragma unroll
        for (int k = 0; k < 3; k++) {
          const float4* W = (const float4*)(dwih + (size_t)rowsQ[k] * 576);
          accg[k] += dot4(W[c], v);
        }
      }
    }
    {
      float4 vh = ((const float4*)dech_s)[lane];
#pragma unroll
      for (int k = 0; k < 3; k++) {
        const float4* Wh = (const float4*)(dwhh + (size_t)rowsQ[k] * 256);
        acch[k] += dot4(Wh[lane], vh);
      }
    }
#pragma unroll
    for (int k = 0; k < 3; k++) {
      int m = wv * 3 + k;
      int gate = m >> 3, idx = m & 7;
      if (gate < 2) {
        float s = warp_sum(accg[k] + acch[k]);
        if (lane == 0) dg_s[gate][idx] = s + dbi_r[k] + dbh_r[k];
      } else {
        float sg = warp_sum(accg[k]);
        float sh = warp_sum(acch[k]);
        if (lane == 0) { dg_s[2][idx] = sg + dbi_r[k]; dg_s[3][idx] = sh + dbh_r[k]; }
      }
    }
  };

  // init state + initial tile + fix(0)
  for (int i = tid; i < 1024; i += NTH) avq_s[i] = (i >= 512) ? 1.f : 0.f;
  if (tid < 256) { h_s[tid] = 0.f; dech_s[tid] = 0.f; }
  {
    const float4* g4 = (const float4*)x_att;
    float4 a = g4[tid * 2], b = g4[tid * 2 + 1];
    int row = tid >> 3, c0 = (tid & 7) * 8;
    float* d = &att_s[row * 65 + c0];
    d[0]=a.x; d[1]=a.y; d[2]=a.z; d[3]=a.w; d[4]=b.x; d[5]=b.y; d[6]=b.z; d[7]=b.w;
  }
  if (tid < 64) xcat_s[tid] = x_fix[tid];
  __syncthreads();

  for (int t = 0; t <= TT; ++t) {
    if (t > 0) {
      // ---- A: poll E1(t-1); deferred zero of qacc buf (t-1)%3 ----
      {
        float f = mbpoll(mb1 + (size_t)((t - 1) & 1) * 512 + tid, (unsigned)t);
        int b = tid >> 4, j = tid & 15;
        if (j < 8) h_s[b * 8 + j] = f;
        else dech_s[b * 8 + j - 8] = f;
        if (t >= 2 && tid < 16)
          __hip_atomic_store(&qacc[(size_t)((t - 1) % 3) * 512 + bid * 16 + tid],
                             0.f, __ATOMIC_RELAXED, __HIP_MEMORY_SCOPE_AGENT);
      }
      __syncthreads();
      // ---- B: hid(t-1) row (1/wave, reg weights) ----
      {
        float hfx = hid_fix[(size_t)(t - 1) * 256 + bid * 8 + wv];
        const float4* h4 = (const float4*)h_s;
        const float4* a4 = (const float4*)avq_s;
        float acc = dot4(wBq[0], h4[lane]) + dot4(wBq[1], a4[lane]) +
                    dot4(wBq[2], a4[64 + lane]);
        float s = warp_sum(acc);
        if (lane == 0) hid8_s[wv] = fmaxf(s + hfx, 0.f);
      }
      __syncthreads();
      // ---- C: query partial add (reg wq slice) + drain ----
      {
        float hv[8];
#pragma unroll
        for (int r = 0; r < 8; r++) hv[r] = hid8_s[r];
        float partial = 0.f;
#pragma unroll
        for (int r = 0; r < 8; r++) partial += hv[r] * wqr[r];
        __hip_atomic_fetch_add(&qacc[(size_t)(t % 3) * 512 + tid], partial,
                               __ATOMIC_RELAXED, __HIP_MEMORY_SCOPE_AGENT);
        asm volatile("s_waitcnt vmcnt(0)" ::: "memory");
      }
      __syncthreads();
      // ---- D1: arrive EARLY (before dec work) ----
      if (tid == 0)
        __hip_atomic_fetch_add(qcnt, 1u, __ATOMIC_RELAXED,
                               __HIP_MEMORY_SCOPE_AGENT);
      // ---- DEC (no query dependence): hidden under arrival skew ----
      if (t < TT) {
        {
          const float* rg = ring_s[(t >= 16) ? (t & 15) : 0];
          float dv = 0.f;
#pragma unroll 8
          for (int n = 0; n < 64; n++) dv += rg[wv * 64 + n] * att_s[n * 65 + lane];
          xcat_s[64 + wv * 64 + lane] = dv;
        }
        __syncthreads();  // S-D1
        dec_gates();
        __syncthreads();  // S-D2
        if (tid < 8) {
          float r = sigf(dg_s[0][tid]), z = sigf(dg_s[1][tid]);
          float nn = tanhf(dg_s[2][tid] + r * dg_s[3][tid]);
          float d2 = (1.f - z) * nn + z * dech_s[bid * 8 + tid];
          astore64(&mb1[(size_t)(t & 1) * 512 + bid * 16 + 8 + tid],
                   mbpack(d2, (unsigned)(t + 1)));
          dec_hist[(size_t)t * 256 + bid * 8 + tid] = d2;
        } else if (tid >= 16 && tid < 32) {
          int k2 = tid - 16;
          dava[(size_t)t * 512 + bid * 16 + k2] = xcat_s[64 + bid * 16 + k2];
        }
      }
      // ---- D2: poll (likely already satisfied) ----
      if (tid == 0) {
        unsigned target = 32u * (unsigned)t;
        while (__hip_atomic_load(qcnt, __ATOMIC_RELAXED,
                                 __HIP_MEMORY_SCOPE_AGENT) < target)
          __builtin_amdgcn_s_sleep(1);
      }
      __syncthreads();
      // ---- E: read summed query(t) ----
      {
        float qv = __hip_atomic_load(&qacc[(size_t)(t % 3) * 512 + tid],
                                     __ATOMIC_RELAXED, __HIP_MEMORY_SCOPE_AGENT);
        avq_s[512 + tid] = qv;
        if (t == TT) {
          if (bid == 0) {
            if (tid < 256) {
              out[OUT_QGRU + tid] = h_s[tid];
              out[OUT_DECGRU + tid] = dech_s[tid];
            }
            out[OUT_QN + tid] = qv;
          }
          break;
        }
      }
      __syncthreads();
    }

    // ---- F: prefetch tile(t+1) + q-attention(t) ----
    float4 pfa, pfb;
    {
      int tn = (t + 1 < TT) ? t + 1 : t;
      const float4* g4 = (const float4*)(x_att + (size_t)tn * 4096);
      pfa = g4[tid * 2];
      pfb = g4[tid * 2 + 1];
    }
    float gfx[3];
#pragma unroll
    for (int k = 0; k < 3; k++) gfx[k] = gi_fix[(size_t)t * 768 + rowsQ[k]];
    {
      float acc = 0.f;
#pragma unroll 16
      for (int a = 0; a < 64; a++)
        acc += avq_s[512 + wv * 64 + a] * att_s[lane * 65 + a];
      acc *= 0.125f;
      float m = __shfl(warp_max(acc), 0, 64);
      float e = __expf(acc - m);
      float s = __shfl(warp_sum(e), 0, 64);
      qk_s[wv * 64 + lane] = e / s;
    }
    {
      float av = 0.f;
#pragma unroll 8
      for (int n = 0; n < 64; n++)
        av += qk_s[wv * 64 + n] * att_s[n * 65 + lane];
      avq_s[wv * 64 + lane] = av;
    }
    if (t == 0) {  // dec_attw[0] = attw[0]; qk row is wave-local
      float dv = 0.f;
#pragma unroll 8
      for (int n = 0; n < 64; n++)
        dv += qk_s[wv * 64 + n] * att_s[n * 65 + lane];
      xcat_s[64 + wv * 64 + lane] = dv;
    }
    __syncthreads();  // S-F
    // ---- G: q-GRU gates (reg weights); t==0 also dec gates ----
    {
      float accg[3], acch[3];
#pragma unroll
      for (int k = 0; k < 3; k++) { accg[k] = 0.f; acch[k] = 0.f; }
      const float4* in4 = (const float4*)avq_s;
#pragma unroll
      for (int c0 = 0; c0 < 4; c0++) {
        float4 v = in4[lane + 64 * c0];
#pragma unroll
        for (int k = 0; k < 3; k++) accg[k] += dot4(wGi[k][c0], v);
      }
      {
        float4 vh = ((const float4*)h_s)[lane];
#pragma unroll
        for (int k = 0; k < 3; k++) acch[k] += dot4(wGh[k], vh);
      }
#pragma unroll
      for (int k = 0; k < 3; k++) {
        int m = wv * 3 + k;
        int gate = m >> 3, idx = m & 7;
        if (gate < 2) {
          float s = warp_sum(accg[k] + acch[k]);
          if (lane == 0) g_s[gate][idx] = s + gfx[k] + bhh_r[k];
        } else {
          float sg = warp_sum(accg[k]);
          float sh = warp_sum(acch[k]);
          if (lane == 0) { g_s[2][idx] = sg + gfx[k]; g_s[3][idx] = sh + bhh_r[k]; }
        }
      }
    }
    if (t == 0) dec_gates();
    __syncthreads();  // S-G
    // ---- H: q combine + E1(t) h2 write ASAP; t==0 also dech ----
    if (tid < 8) {
      float r = sigf(g_s[0][tid]), z = sigf(g_s[1][tid]);
      float nn = tanhf(g_s[2][tid] + r * g_s[3][tid]);
      float h2 = (1.f - z) * nn + z * h_s[bid * 8 + tid];
      astore64(&mb1[(size_t)(t & 1) * 512 + bid * 16 + tid],
               mbpack(h2, (unsigned)(t + 1)));
    } else if (t == 0 && tid < 16) {
      int i = tid - 8;
      float r = sigf(dg_s[0][i]), z = sigf(dg_s[1][i]);
      float nn = tanhf(dg_s[2][i] + r * dg_s[3][i]);
      float d2 = (1.f - z) * nn + z * dech_s[bid * 8 + i];
      astore64(&mb1[(size_t)(t & 1) * 512 + bid * 16 + tid],
               mbpack(d2, (unsigned)(t + 1)));
      dec_hist[(size_t)t * 256 + bid * 8 + i] = d2;
    }
    // ---- I: shadow work ----
    if (tid < 16) {
      out[OUT_ATTW + (size_t)t * 512 + bid * 16 + tid] = qk_s[bid * 16 + tid];
      if (t == 0)
        dava[(size_t)t * 512 + bid * 16 + tid] = xcat_s[64 + bid * 16 + tid];
    }
    ring_s[t & 15][tid] = qk_s[tid];
    {
      int row = tid >> 3, c0 = (tid & 7) * 8;
      float* d = &att_s[row * 65 + c0];
      d[0]=pfa.x; d[1]=pfa.y; d[2]=pfa.z; d[3]=pfa.w;
      d[4]=pfb.x; d[5]=pfb.y; d[6]=pfb.z; d[7]=pfb.w;
    }
    if (tid >= 448) {
      int i = tid - 448;
      int tn = (t + 1 < TT) ? t + 1 : t;
      xcat_s[i] = x_fix[tn * 64 + i];
    }
  }
}

// ---------------- feat assembly: [dec_h | x_fix | dec_att_a] ----------------
__global__ void featcopy(const float* __restrict__ dec_hist,
                         const float* __restrict__ x_fix,
                         const float* __restrict__ dava,
                         float* __restrict__ feat) {
  int t = blockIdx.x, tid = threadIdx.x;
  float* f = feat + (size_t)t * 832;
  f[tid] = dec_hist[(size_t)t * 256 + tid];
  if (tid < 64) f[256 + tid] = x_fix[t * 64 + tid];
  for (int i = tid; i < 512; i += 256) f[320 + i] = dava[(size_t)t * 512 + i];
}

// ---------------- final MLP ----------------
__global__ void __launch_bounds__(256) final_k(
    const float* __restrict__ x_att,
    const float* __restrict__ s,      // [2048,256] shared part incl. b1
    const float* __restrict__ w1,     // dec_hid_w [256,896]
    const float* __restrict__ w2T,    // [256,64]
    const float* __restrict__ b2,     // [64]
    float* __restrict__ pred) {
  __shared__ float att_s[4096];
  __shared__ float s_s[256];
  __shared__ float hid_s[32 * 256];
  int t = blockIdx.x, tid = threadIdx.x, lane = tid & 63, wv = tid >> 6;
  for (int i = tid; i < 4096; i += 256) att_s[i] = x_att[(size_t)t * 4096 + i];
  s_s[tid] = s[(size_t)t * 256 + tid];
  float4 w1v[16];
  const float4* W1a4 = (const float4*)(w1 + (size_t)tid * 896 + 832);
#pragma unroll
  for (int q = 0; q < 16; q++) w1v[q] = W1a4[q];
  float bb = b2[lane];
  __syncthreads();
  for (int ch = 0; ch < 2; ch++) {
    for (int nl = 0; nl < 32; nl++) {
      int n = ch * 32 + nl;
      const float4* a4 = (const float4*)(att_s + n * 64);
      float acc = s_s[tid];
#pragma unroll
      for (int q = 0; q < 16; q++) acc += dot4(w1v[q], a4[q]);
      hid_s[nl * 256 + tid] = fmaxf(acc, 0.f);
    }
    __syncthreads();
    float accb[8];
#pragma unroll
    for (int j = 0; j < 8; j++) accb[j] = bb;
    for (int r = 0; r < 256; r++) {
      float w = w2T[r * 64 + lane];
#pragma unroll
      for (int j = 0; j < 8; j++) accb[j] += w * hid_s[(wv * 8 + j) * 256 + r];
    }
#pragma unroll
    for (int j = 0; j < 8; j++) {
      int n = ch * 32 + wv * 8 + j;
      pred[(size_t)t * 4096 + n * 64 + lane] = fmaxf(accb[j], 0.f);
    }
    __syncthreads();
  }
}

extern "C" void kernel_launch(void* const* d_in, const int* in_sizes, int n_in,
                              void* d_out, int out_size, void* d_ws, size_t ws_size,
                              hipStream_t stream) {
  const float* x_fix = (const float*)d_in[0];
  const float* x_att = (const float*)d_in[1];
  const float* qwih = (const float*)d_in[3];
  const float* qwhh = (const float*)d_in[4];
  const float* qbih = (const float*)d_in[5];
  const float* qbhh = (const float*)d_in[6];
  const float* qhw = (const float*)d_in[7];
  const float* qhb = (const float*)d_in[8];
  const float* wq = (const float*)d_in[9];
  const float* dwih = (const float*)d_in[10];
  const float* dwhh = (const float*)d_in[11];
  const float* dbih = (const float*)d_in[12];
  const float* dbhh = (const float*)d_in[13];
  const float* w1 = (const float*)d_in[14];
  const float* b1 = (const float*)d_in[15];
  const float* w2 = (const float*)d_in[16];
  const float* b2 = (const float*)d_in[17];
  float* out = (float*)d_out;

  char* ws = (char*)d_ws;
  unsigned long long* mb1 = (unsigned long long*)(ws + WSO_MB1);
  float* qacc = (float*)(ws + WSO_QACC);
  unsigned* qcnt = (unsigned*)(ws + WSO_QCNT);
  float* gi_fix = (float*)(ws + WSO_GIFIX);
  float* hid_fix = (float*)(ws + WSO_HIDFIX);
  float* w2T = (float*)(ws + WSO_W2T);
  float* dava = (float*)(ws + WSO_DAVA);
  float* dec_hist = (float*)(ws + WSO_DECH);
  float* feat = (float*)(ws + WSO_FEAT);
  float* sbuf = (float*)(ws + WSO_SBUF);

  // zero mailbox tags + query accumulator + counter — required every launch
  hipMemsetAsync(ws, 0, WSO_ZEND, stream);

  transpose_k<<<64, 256, 0, stream>>>(w2, w2T);
  gemm64<<<dim3(32, 12), 256, 0, stream>>>(x_fix, 64, qwih, 1088, 0, qbih,
                                           gi_fix, 768, 64);
  gemm64<<<dim3(32, 4), 256, 0, stream>>>(x_fix, 64, qhw, 832, 256, qhb,
                                          hid_fix, 256, 64);

  seq_kernel<<<NBLK, NTH, 0, stream>>>(x_fix, x_att, qwih, qwhh, qbhh,
                                       qhw, wq, dwih, dwhh, dbih, dbhh,
                                       gi_fix, hid_fix, mb1, qacc, qcnt,
                                       dava, dec_hist, out);

  featcopy<<<2048, 256, 0, stream>>>(dec_hist, x_fix, dava, feat);
  gemm64<<<dim3(32, 4), 256, 0, stream>>>(feat, 832, w1, 896, 0, b1,
                                          sbuf, 256, 832);
  final_k<<<2048, 256, 0, stream>>>(x_att, sbuf, w1, w2T, b2, out);
}